// Round 1
// baseline (147.918 us; speedup 1.0000x reference)
//
#include <hip/hip_runtime.h>
#include <cstdint>
#include <cstddef>

typedef short bf16x8 __attribute__((ext_vector_type(8)));
typedef float f32x4 __attribute__((ext_vector_type(4)));

#define BN 8
#define TN 2048
#define CN 1024
#define HN 64

__device__ __forceinline__ unsigned short f2bf(float f) {
    unsigned int u = __float_as_uint(f);
    u += 0x7fffu + ((u >> 16) & 1u);
    return (unsigned short)(u >> 16);
}

// Build Wct[n][c] (bf16), n in [0,192): n<64 = Wq col h (pre-scaled by 0.125*log2e),
// 64..127 = Wk col, 128..191 = Wv col.  Source W is [C][H] row-major.
__global__ __launch_bounds__(256) void wconv_kernel(const float* __restrict__ Wq,
                                                    const float* __restrict__ Wk,
                                                    const float* __restrict__ Wv,
                                                    unsigned short* __restrict__ Wct) {
    int idx = blockIdx.x * 256 + threadIdx.x;   // 0..196607
    int n = idx >> 10;
    int c = idx & 1023;
    int m = n >> 6;
    int h = n & 63;
    const float* W = (m == 0) ? Wq : ((m == 1) ? Wk : Wv);
    float v = W[c * 64 + h];
    if (m == 0) v *= 0.18033688011112042f;  // (1/sqrt(64)) * log2(e)
    Wct[idx] = f2bf(v);
}

// Fused QKV projection: X[16384][1024] fp32 @ Wct^T -> Qs/Ks [16384][64] bf16,
// Vt [8][64][2048] bf16 (transposed).  32 rows per block, 4 waves, wave w owns
// output cols [48w, 48w+48).  mfma_f32_16x16x32_bf16, no LDS.
__global__ __launch_bounds__(256) void proj_kernel(const float* __restrict__ X,
                                                   const unsigned short* __restrict__ Wct,
                                                   unsigned short* __restrict__ Qs,
                                                   unsigned short* __restrict__ Ks,
                                                   unsigned short* __restrict__ Vt) {
    const int tid = threadIdx.x;
    const int w   = tid >> 6;
    const int l   = tid & 63;
    const int lq  = l & 15;
    const int lg  = l >> 4;
    const int rowbase = blockIdx.x * 32;

    const f32x4 zero4 = {0.f, 0.f, 0.f, 0.f};
    f32x4 acc[2][3];
    #pragma unroll
    for (int mi = 0; mi < 2; ++mi)
        #pragma unroll
        for (int j = 0; j < 3; ++j)
            acc[mi][j] = zero4;

    const float* xbase0 = X + (size_t)(rowbase + lq) * CN;
    const float* xbase1 = X + (size_t)(rowbase + 16 + lq) * CN;
    const unsigned short* wbase0 = Wct + (size_t)(w * 48 + 0 * 16 + lq) * CN;
    const unsigned short* wbase1 = Wct + (size_t)(w * 48 + 1 * 16 + lq) * CN;
    const unsigned short* wbase2 = Wct + (size_t)(w * 48 + 2 * 16 + lq) * CN;

    for (int kk = 0; kk < 32; ++kk) {
        const int k0 = kk * 32 + lg * 8;
        bf16x8 a[2];
        #pragma unroll
        for (int mi = 0; mi < 2; ++mi) {
            const float* xp = (mi == 0 ? xbase0 : xbase1) + k0;
            float4 x0 = *(const float4*)xp;
            float4 x1 = *(const float4*)(xp + 4);
            bf16x8 t;
            t[0] = (short)f2bf(x0.x); t[1] = (short)f2bf(x0.y);
            t[2] = (short)f2bf(x0.z); t[3] = (short)f2bf(x0.w);
            t[4] = (short)f2bf(x1.x); t[5] = (short)f2bf(x1.y);
            t[6] = (short)f2bf(x1.z); t[7] = (short)f2bf(x1.w);
            a[mi] = t;
        }
        bf16x8 b0 = *(const bf16x8*)(wbase0 + k0);
        bf16x8 b1 = *(const bf16x8*)(wbase1 + k0);
        bf16x8 b2 = *(const bf16x8*)(wbase2 + k0);
        acc[0][0] = __builtin_amdgcn_mfma_f32_16x16x32_bf16(a[0], b0, acc[0][0], 0, 0, 0);
        acc[1][0] = __builtin_amdgcn_mfma_f32_16x16x32_bf16(a[1], b0, acc[1][0], 0, 0, 0);
        acc[0][1] = __builtin_amdgcn_mfma_f32_16x16x32_bf16(a[0], b1, acc[0][1], 0, 0, 0);
        acc[1][1] = __builtin_amdgcn_mfma_f32_16x16x32_bf16(a[1], b1, acc[1][1], 0, 0, 0);
        acc[0][2] = __builtin_amdgcn_mfma_f32_16x16x32_bf16(a[0], b2, acc[0][2], 0, 0, 0);
        acc[1][2] = __builtin_amdgcn_mfma_f32_16x16x32_bf16(a[1], b2, acc[1][2], 0, 0, 0);
    }

    // D layout: col = lane&15, row = 4*(lane>>4) + reg
    #pragma unroll
    for (int mi = 0; mi < 2; ++mi) {
        #pragma unroll
        for (int j = 0; j < 3; ++j) {
            const int col = w * 48 + j * 16 + lq;
            const int mtx = col >> 6;          // 0=Q, 1=K, 2=V
            const int h   = col & 63;
            #pragma unroll
            for (int i = 0; i < 4; ++i) {
                const int g = rowbase + 16 * mi + 4 * lg + i;  // global row
                const unsigned short val = f2bf(acc[mi][j][i]);
                if (mtx == 0) {
                    Qs[(size_t)g * 64 + h] = val;
                } else if (mtx == 1) {
                    Ks[(size_t)g * 64 + h] = val;
                } else {
                    const int bb = g >> 11, t = g & 2047;
                    Vt[(size_t)((bb << 6) + h) * 2048 + t] = val;
                }
            }
        }
    }
}

// Flash attention, causal.  1 wave / 16 queries; key tiles of 32.
// S^T = mfma(K, Q): lane&15 = query, key = 16*fa + 4*(lane>>4) + reg.
// PV: A-slot i <-> (frag i>>2, reg i&3), V loaded with the matching k-map.
__global__ __launch_bounds__(64) void attn_kernel(const unsigned short* __restrict__ Qs,
                                                  const unsigned short* __restrict__ Ks,
                                                  const unsigned short* __restrict__ Vt,
                                                  float* __restrict__ Out) {
    const int l  = threadIdx.x;
    const int lq = l & 15;
    const int lg = l >> 4;
    const int bid = blockIdx.x;
    const int b  = bid >> 7;
    const int qt = 127 - (bid & 127);   // heavy q-tiles first
    const int q0 = qt * 16;

    const unsigned short* Qb = Qs + (size_t)b * TN * 64;
    const unsigned short* Kb = Ks + (size_t)b * TN * 64;
    const unsigned short* Vb = Vt + (size_t)b * 64 * TN;

    bf16x8 qa[2];
    #pragma unroll
    for (int ks = 0; ks < 2; ++ks)
        qa[ks] = *(const bf16x8*)(Qb + (size_t)(q0 + lq) * 64 + ks * 32 + lg * 8);

    const f32x4 zero4 = {0.f, 0.f, 0.f, 0.f};
    f32x4 acc[4];
    #pragma unroll
    for (int nf = 0; nf < 4; ++nf) acc[nf] = zero4;
    float mrow = -1e30f;
    float lrow = 0.f;

    const int ktmax = (q0 + 15) >> 5;
    for (int kt = 0; kt <= ktmax; ++kt) {
        const int key0 = kt * 32;
        f32x4 s[2] = {zero4, zero4};
        #pragma unroll
        for (int fa = 0; fa < 2; ++fa) {
            #pragma unroll
            for (int ks = 0; ks < 2; ++ks) {
                bf16x8 ka = *(const bf16x8*)(Kb + (size_t)(key0 + fa * 16 + lq) * 64 + ks * 32 + lg * 8);
                s[fa] = __builtin_amdgcn_mfma_f32_16x16x32_bf16(ka, qa[ks], s[fa], 0, 0, 0);
            }
        }
        // causal mask (only the diagonal-adjacent tiles need it)
        if (key0 + 32 > q0) {
            const int q = q0 + lq;
            #pragma unroll
            for (int fa = 0; fa < 2; ++fa)
                #pragma unroll
                for (int r = 0; r < 4; ++r) {
                    const int key = key0 + fa * 16 + 4 * lg + r;
                    if (key > q) s[fa][r] = -1e30f;
                }
        }
        // online softmax (stats in lane&15 domain, replicated over lg via shfl_xor)
        float tm = s[0][0];
        #pragma unroll
        for (int fa = 0; fa < 2; ++fa)
            #pragma unroll
            for (int r = 0; r < 4; ++r) tm = fmaxf(tm, s[fa][r]);
        tm = fmaxf(tm, __shfl_xor(tm, 16));
        tm = fmaxf(tm, __shfl_xor(tm, 32));
        const float mnew = fmaxf(mrow, tm);
        float p[2][4];
        float psum = 0.f;
        #pragma unroll
        for (int fa = 0; fa < 2; ++fa)
            #pragma unroll
            for (int r = 0; r < 4; ++r) {
                p[fa][r] = __builtin_amdgcn_exp2f(s[fa][r] - mnew);
                psum += p[fa][r];
            }
        psum += __shfl_xor(psum, 16);
        psum += __shfl_xor(psum, 32);
        const float c = __builtin_amdgcn_exp2f(mrow - mnew);
        lrow = lrow * c + psum;
        mrow = mnew;

        // rescale acc: acc element i belongs to query 4*lg + i -> fetch its c
        float cb[4];
        #pragma unroll
        for (int i = 0; i < 4; ++i) cb[i] = __shfl(c, 4 * lg + i);
        #pragma unroll
        for (int nf = 0; nf < 4; ++nf)
            #pragma unroll
            for (int i = 0; i < 4; ++i) acc[nf][i] *= cb[i];

        // P as PV A-operand: slot i <-> (fa = i>>2, reg = i&3)
        bf16x8 pa;
        pa[0] = (short)f2bf(p[0][0]); pa[1] = (short)f2bf(p[0][1]);
        pa[2] = (short)f2bf(p[0][2]); pa[3] = (short)f2bf(p[0][3]);
        pa[4] = (short)f2bf(p[1][0]); pa[5] = (short)f2bf(p[1][1]);
        pa[6] = (short)f2bf(p[1][2]); pa[7] = (short)f2bf(p[1][3]);

        #pragma unroll
        for (int nf = 0; nf < 4; ++nf) {
            const unsigned short* vp = Vb + (size_t)(nf * 16 + lq) * TN + key0 + 4 * lg;
            ushort4 v0 = *(const ushort4*)vp;
            ushort4 v1 = *(const ushort4*)(vp + 16);
            bf16x8 vb;
            vb[0] = (short)v0.x; vb[1] = (short)v0.y; vb[2] = (short)v0.z; vb[3] = (short)v0.w;
            vb[4] = (short)v1.x; vb[5] = (short)v1.y; vb[6] = (short)v1.z; vb[7] = (short)v1.w;
            acc[nf] = __builtin_amdgcn_mfma_f32_16x16x32_bf16(pa, vb, acc[nf], 0, 0, 0);
        }
    }

    // epilogue: out[q][h] = acc / l_row(q);  q = q0 + 4*lg + i, h = 16*nf + lq
    float li[4];
    #pragma unroll
    for (int i = 0; i < 4; ++i) li[i] = 1.0f / __shfl(lrow, 4 * lg + i);
    #pragma unroll
    for (int nf = 0; nf < 4; ++nf)
        #pragma unroll
        for (int i = 0; i < 4; ++i) {
            const int q = q0 + 4 * lg + i;
            Out[((size_t)b * TN + q) * 64 + nf * 16 + lq] = acc[nf][i] * li[i];
        }
}

extern "C" void kernel_launch(void* const* d_in, const int* in_sizes, int n_in,
                              void* d_out, int out_size, void* d_ws, size_t ws_size,
                              hipStream_t stream) {
    const float* X  = (const float*)d_in[0];
    const float* Wq = (const float*)d_in[1];
    const float* Wk = (const float*)d_in[2];
    const float* Wv = (const float*)d_in[3];
    float* Out = (float*)d_out;

    char* ws = (char*)d_ws;
    unsigned short* Wct = (unsigned short*)(ws);                          // 384 KB
    unsigned short* Qs  = (unsigned short*)(ws + (1u << 20));             // 2 MB
    unsigned short* Ks  = (unsigned short*)(ws + (1u << 20) + (2u << 20)); // 2 MB
    unsigned short* Vt  = (unsigned short*)(ws + (1u << 20) + (4u << 20)); // 2 MB

    hipLaunchKernelGGL(wconv_kernel, dim3(768), dim3(256), 0, stream, Wq, Wk, Wv, Wct);
    hipLaunchKernelGGL(proj_kernel,  dim3(512), dim3(256), 0, stream, X, Wct, Qs, Ks, Vt);
    hipLaunchKernelGGL(attn_kernel,  dim3(1024), dim3(64), 0, stream, Qs, Ks, Vt, Out);
}

// Round 2
// 145.956 us; speedup vs baseline: 1.0134x; 1.0134x over previous
//
#include <hip/hip_runtime.h>
#include <cstdint>
#include <cstddef>

typedef short bf16x8 __attribute__((ext_vector_type(8)));
typedef float f32x4 __attribute__((ext_vector_type(4)));

#define BN 8
#define TN 2048
#define CN 1024
#define HN 64

__device__ __forceinline__ unsigned short f2bf(float f) {
    unsigned int u = __float_as_uint(f);
    u += 0x7fffu + ((u >> 16) & 1u);
    return (unsigned short)(u >> 16);
}

// Build Wct[n][c] (bf16), n in [0,192): n<64 = Wq col h (pre-scaled by 0.125*log2e),
// 64..127 = Wk col, 128..191 = Wv col.  Source W is [C][H] row-major.
__global__ __launch_bounds__(256) void wconv_kernel(const float* __restrict__ Wq,
                                                    const float* __restrict__ Wk,
                                                    const float* __restrict__ Wv,
                                                    unsigned short* __restrict__ Wct) {
    int idx = blockIdx.x * 256 + threadIdx.x;   // 0..196607
    int n = idx >> 10;
    int c = idx & 1023;
    int m = n >> 6;
    int h = n & 63;
    const float* W = (m == 0) ? Wq : ((m == 1) ? Wk : Wv);
    float v = W[c * 64 + h];
    if (m == 0) v *= 0.18033688011112042f;  // (1/sqrt(64)) * log2(e)
    Wct[idx] = f2bf(v);
}

// Fused QKV projection v2: X[16384][1024] fp32 staged once through LDS as bf16
// (XOR-swizzled), 8 waves/block (2 row-groups x 4 col-groups), 32 rows/block.
__global__ __launch_bounds__(512) void proj_kernel(const float* __restrict__ X,
                                                   const unsigned short* __restrict__ Wct,
                                                   unsigned short* __restrict__ Qs,
                                                   unsigned short* __restrict__ Ks,
                                                   unsigned short* __restrict__ Vt) {
    __shared__ short Xs[32 * 1024];   // 64 KB, bf16, swizzled
    char* XsB = (char*)Xs;

    const int tid = threadIdx.x;
    const int rowbase = blockIdx.x * 32;

    // stage: 512 threads x 8 iters x 8 elems = 32768 elems
    #pragma unroll
    for (int i = 0; i < 8; ++i) {
        const int off = i * 4096 + tid * 8;
        const int row = off >> 10;
        const int col = off & 1023;
        const float* xp = X + (size_t)(rowbase + row) * CN + col;
        float4 x0 = *(const float4*)xp;
        float4 x1 = *(const float4*)(xp + 4);
        bf16x8 t;
        t[0] = (short)f2bf(x0.x); t[1] = (short)f2bf(x0.y);
        t[2] = (short)f2bf(x0.z); t[3] = (short)f2bf(x0.w);
        t[4] = (short)f2bf(x1.x); t[5] = (short)f2bf(x1.y);
        t[6] = (short)f2bf(x1.z); t[7] = (short)f2bf(x1.w);
        int addr = (row * 2048 + col * 2) ^ ((row & 7) << 4);
        *(bf16x8*)(XsB + addr) = t;
    }
    __syncthreads();

    const int w  = tid >> 6;        // 0..7
    const int l  = tid & 63;
    const int lq = l & 15;
    const int lg = l >> 4;
    const int wr = w >> 2;          // row-group (16 rows)
    const int wc = w & 3;           // col-group (48 cols)

    const f32x4 zero4 = {0.f, 0.f, 0.f, 0.f};
    f32x4 acc[3] = {zero4, zero4, zero4};

    const unsigned short* wbase0 = Wct + (size_t)(wc * 48 + 0 * 16 + lq) * CN;
    const unsigned short* wbase1 = Wct + (size_t)(wc * 48 + 1 * 16 + lq) * CN;
    const unsigned short* wbase2 = Wct + (size_t)(wc * 48 + 2 * 16 + lq) * CN;

    const int arow = wr * 16 + lq;
    const int abase = arow * 2048;
    const int aswz = (arow & 7) << 4;

    for (int kk = 0; kk < 32; ++kk) {
        const int k0 = kk * 32 + lg * 8;
        bf16x8 a = *(const bf16x8*)(XsB + (abase + ((kk * 64 + lg * 16) ^ aswz)));
        bf16x8 b0 = *(const bf16x8*)(wbase0 + k0);
        bf16x8 b1 = *(const bf16x8*)(wbase1 + k0);
        bf16x8 b2 = *(const bf16x8*)(wbase2 + k0);
        acc[0] = __builtin_amdgcn_mfma_f32_16x16x32_bf16(a, b0, acc[0], 0, 0, 0);
        acc[1] = __builtin_amdgcn_mfma_f32_16x16x32_bf16(a, b1, acc[1], 0, 0, 0);
        acc[2] = __builtin_amdgcn_mfma_f32_16x16x32_bf16(a, b2, acc[2], 0, 0, 0);
    }

    // D layout: col = lane&15, row = 4*(lane>>4) + reg
    #pragma unroll
    for (int j = 0; j < 3; ++j) {
        const int col = wc * 48 + j * 16 + lq;
        const int mtx = col >> 6;          // 0=Q, 1=K, 2=V
        const int h   = col & 63;
        #pragma unroll
        for (int i = 0; i < 4; ++i) {
            const int g = rowbase + wr * 16 + 4 * lg + i;  // global row
            const unsigned short val = f2bf(acc[j][i]);
            if (mtx == 0) {
                Qs[(size_t)g * 64 + h] = val;
            } else if (mtx == 1) {
                Ks[(size_t)g * 64 + h] = val;
            } else {
                const int bb = g >> 11, t = g & 2047;
                Vt[(size_t)((bb << 6) + h) * 2048 + t] = val;
            }
        }
    }
}

// Split-K flash attention, causal.  Each wave: one (q-tile, key-chunk) job,
// chunk = CT=2^shift key-tiles of 32.  Writes partial (m,l,acc) unless finalw.
// S^T = mfma(K, Q): lane&15 = query, key = 16*fa + 4*(lane>>4) + reg.
__global__ __launch_bounds__(256) void attn_kernel(const unsigned short* __restrict__ Qs,
                                                   const unsigned short* __restrict__ Ks,
                                                   const unsigned short* __restrict__ Vt,
                                                   float* __restrict__ Pm,
                                                   float* __restrict__ Pl,
                                                   float* __restrict__ Pacc,
                                                   float* __restrict__ Out,
                                                   int shift, int jpb, int finalw, int totalJobs) {
    const int l  = threadIdx.x & 63;
    const int wid = threadIdx.x >> 6;
    const int j = blockIdx.x * 4 + wid;
    if (j >= totalJobs) return;
    const int lq = l & 15;
    const int lg = l >> 4;

    const int b  = j / jpb;
    const int jb = j - b * jpb;
    // map jb -> (qt, chunk)
    int base = 0, a = 0, nc = 1;
    for (a = 0; a < 64; ++a) {
        nc = (a >> shift) + 1;
        const int span = nc << 1;
        if (jb < base + span) break;
        base += span;
    }
    const int off = jb - base;
    const int qt = 2 * a + (off >= nc ? 1 : 0);
    const int c  = (off >= nc) ? off - nc : off;
    const int q0 = qt * 16;
    const int ntiles = (qt >> 1) + 1;
    const int CT = 1 << shift;
    const int t0 = c * CT;
    int t1 = t0 + CT; if (t1 > ntiles) t1 = ntiles;

    const unsigned short* Qb = Qs + (size_t)b * TN * 64;
    const unsigned short* Kb = Ks + (size_t)b * TN * 64;
    const unsigned short* Vb = Vt + (size_t)b * 64 * TN;

    bf16x8 qa[2];
    #pragma unroll
    for (int ks = 0; ks < 2; ++ks)
        qa[ks] = *(const bf16x8*)(Qb + (size_t)(q0 + lq) * 64 + ks * 32 + lg * 8);

    const f32x4 zero4 = {0.f, 0.f, 0.f, 0.f};
    f32x4 acc[4];
    #pragma unroll
    for (int nf = 0; nf < 4; ++nf) acc[nf] = zero4;
    float mrow = -1e30f;
    float lrow = 0.f;

    for (int kt = t0; kt < t1; ++kt) {
        const int key0 = kt * 32;
        f32x4 s[2] = {zero4, zero4};
        #pragma unroll
        for (int fa = 0; fa < 2; ++fa) {
            #pragma unroll
            for (int ks = 0; ks < 2; ++ks) {
                bf16x8 ka = *(const bf16x8*)(Kb + (size_t)(key0 + fa * 16 + lq) * 64 + ks * 32 + lg * 8);
                s[fa] = __builtin_amdgcn_mfma_f32_16x16x32_bf16(ka, qa[ks], s[fa], 0, 0, 0);
            }
        }
        if (key0 + 32 > q0) {   // causal mask near diagonal
            const int q = q0 + lq;
            #pragma unroll
            for (int fa = 0; fa < 2; ++fa)
                #pragma unroll
                for (int r = 0; r < 4; ++r) {
                    const int key = key0 + fa * 16 + 4 * lg + r;
                    if (key > q) s[fa][r] = -1e30f;
                }
        }
        // online softmax (stats live in lane&15 = query domain)
        float tm = s[0][0];
        #pragma unroll
        for (int fa = 0; fa < 2; ++fa)
            #pragma unroll
            for (int r = 0; r < 4; ++r) tm = fmaxf(tm, s[fa][r]);
        tm = fmaxf(tm, __shfl_xor(tm, 16));
        tm = fmaxf(tm, __shfl_xor(tm, 32));
        const float mnew = fmaxf(mrow, tm);
        float p[2][4];
        float psum = 0.f;
        #pragma unroll
        for (int fa = 0; fa < 2; ++fa)
            #pragma unroll
            for (int r = 0; r < 4; ++r) {
                p[fa][r] = __builtin_amdgcn_exp2f(s[fa][r] - mnew);
                psum += p[fa][r];
            }
        psum += __shfl_xor(psum, 16);
        psum += __shfl_xor(psum, 32);
        const float cc = __builtin_amdgcn_exp2f(mrow - mnew);
        lrow = lrow * cc + psum;
        mrow = mnew;

        float cb[4];
        #pragma unroll
        for (int i = 0; i < 4; ++i) cb[i] = __shfl(cc, 4 * lg + i);
        #pragma unroll
        for (int nf = 0; nf < 4; ++nf)
            #pragma unroll
            for (int i = 0; i < 4; ++i) acc[nf][i] *= cb[i];

        bf16x8 pa;
        pa[0] = (short)f2bf(p[0][0]); pa[1] = (short)f2bf(p[0][1]);
        pa[2] = (short)f2bf(p[0][2]); pa[3] = (short)f2bf(p[0][3]);
        pa[4] = (short)f2bf(p[1][0]); pa[5] = (short)f2bf(p[1][1]);
        pa[6] = (short)f2bf(p[1][2]); pa[7] = (short)f2bf(p[1][3]);

        #pragma unroll
        for (int nf = 0; nf < 4; ++nf) {
            const unsigned short* vp = Vb + (size_t)(nf * 16 + lq) * TN + key0 + 4 * lg;
            ushort4 v0 = *(const ushort4*)vp;
            ushort4 v1 = *(const ushort4*)(vp + 16);
            bf16x8 vb;
            vb[0] = (short)v0.x; vb[1] = (short)v0.y; vb[2] = (short)v0.z; vb[3] = (short)v0.w;
            vb[4] = (short)v1.x; vb[5] = (short)v1.y; vb[6] = (short)v1.z; vb[7] = (short)v1.w;
            acc[nf] = __builtin_amdgcn_mfma_f32_16x16x32_bf16(pa, vb, acc[nf], 0, 0, 0);
        }
    }

    if (finalw) {
        float li[4];
        #pragma unroll
        for (int i = 0; i < 4; ++i) li[i] = 1.0f / __shfl(lrow, 4 * lg + i);
        #pragma unroll
        for (int nf = 0; nf < 4; ++nf)
            #pragma unroll
            for (int i = 0; i < 4; ++i) {
                const int q = q0 + 4 * lg + i;
                Out[((size_t)b * TN + q) * 64 + nf * 16 + lq] = acc[nf][i] * li[i];
            }
    } else {
        if (lg == 0) {
            Pm[(size_t)j * 16 + lq] = mrow;
            Pl[(size_t)j * 16 + lq] = lrow;
        }
        #pragma unroll
        for (int nf = 0; nf < 4; ++nf)
            #pragma unroll
            for (int i = 0; i < 4; ++i)
                Pacc[(size_t)j * 1024 + (4 * lg + i) * 64 + nf * 16 + lq] = acc[nf][i];
    }
}

// Merge up to nc partials per (b, q-tile).
__global__ __launch_bounds__(256) void combine_kernel(const float* __restrict__ Pm,
                                                      const float* __restrict__ Pl,
                                                      const float* __restrict__ Pacc,
                                                      float* __restrict__ Out,
                                                      int shift, int jpb) {
    const int bq = blockIdx.x;
    const int b  = bq >> 7;
    const int qt = bq & 127;
    const int t  = threadIdx.x;
    const int h  = t & 63;
    const int qr = t >> 6;      // 0..3

    const int a = qt >> 1;
    const int m = a >> shift;
    const int r = a & ((1 << shift) - 1);
    const int CT = 1 << shift;
    const int nc = m + 1;
    const int base = 2 * (a + CT * (m * (m - 1) / 2) + r * m);
    const int j0 = b * jpb + base + (qt & 1) * nc;

    for (int qi = 0; qi < 4; ++qi) {
        const int q = qr * 4 + qi;
        float M = -1e30f;
        for (int c = 0; c < nc; ++c)
            M = fmaxf(M, Pm[(size_t)(j0 + c) * 16 + q]);
        float L = 0.f, o = 0.f;
        for (int c = 0; c < nc; ++c) {
            const float w = __builtin_amdgcn_exp2f(Pm[(size_t)(j0 + c) * 16 + q] - M);
            L += w * Pl[(size_t)(j0 + c) * 16 + q];
            o += w * Pacc[(size_t)(j0 + c) * 1024 + q * 64 + h];
        }
        Out[((size_t)b * TN + qt * 16 + q) * 64 + h] = o / L;
    }
}

extern "C" void kernel_launch(void* const* d_in, const int* in_sizes, int n_in,
                              void* d_out, int out_size, void* d_ws, size_t ws_size,
                              hipStream_t stream) {
    const float* X  = (const float*)d_in[0];
    const float* Wq = (const float*)d_in[1];
    const float* Wk = (const float*)d_in[2];
    const float* Wv = (const float*)d_in[3];
    float* Out = (float*)d_out;

    char* ws = (char*)d_ws;
    unsigned short* Wct = (unsigned short*)(ws);                 // 384 KB (pad 512 KB)
    unsigned short* Qs  = (unsigned short*)(ws + (512u << 10));  // 2 MB
    unsigned short* Ks  = Qs + (size_t)16384 * 64;               // 2 MB
    unsigned short* Vt  = Ks + (size_t)16384 * 64;               // 2 MB
    const size_t fixed_end = (512u << 10) + 3u * ((size_t)16384 * 64 * 2);  // 6.5 MB

    // pick split factor: CT = 2^shift key-tiles per job; prefer finest that fits ws
    int shift = 6, jpb = 128;
    for (int s = 3; s <= 4; ++s) {
        int tot = 0;
        for (int a = 0; a < 64; ++a) tot += 2 * ((a >> s) + 1);
        const size_t J = 8u * (size_t)tot;
        const size_t need = fixed_end + J * 128 + J * 4096;
        if (need <= ws_size) { shift = s; jpb = tot; break; }
    }
    const int totalJobs = 8 * jpb;
    const int finalw = (shift == 6) ? 1 : 0;

    float* Pm   = (float*)(ws + fixed_end);
    float* Pl   = Pm + (size_t)totalJobs * 16;
    float* Pacc = (float*)(ws + fixed_end + (size_t)totalJobs * 128);

    hipLaunchKernelGGL(wconv_kernel, dim3(768), dim3(256), 0, stream, Wq, Wk, Wv, Wct);
    hipLaunchKernelGGL(proj_kernel,  dim3(512), dim3(512), 0, stream, X, Wct, Qs, Ks, Vt);
    hipLaunchKernelGGL(attn_kernel,  dim3((totalJobs + 3) / 4), dim3(256), 0, stream,
                       Qs, Ks, Vt, Pm, Pl, Pacc, Out, shift, jpb, finalw, totalJobs);
    if (!finalw)
        hipLaunchKernelGGL(combine_kernel, dim3(1024), dim3(256), 0, stream,
                           Pm, Pl, Pacc, Out, shift, jpb);
}

// Round 3
// 109.527 us; speedup vs baseline: 1.3505x; 1.3326x over previous
//
#include <hip/hip_runtime.h>
#include <cstdint>
#include <cstddef>

typedef short bf16x8 __attribute__((ext_vector_type(8)));
typedef float f32x4 __attribute__((ext_vector_type(4)));

#define BN 8
#define TN 2048
#define CN 1024
#define HN 64

__device__ __forceinline__ unsigned short f2bf(float f) {
    unsigned int u = __float_as_uint(f);
    u += 0x7fffu + ((u >> 16) & 1u);
    return (unsigned short)(u >> 16);
}

// Build Wct[n][c] (bf16), n in [0,192): n<64 = Wq col h (pre-scaled by 0.125*log2e),
// 64..127 = Wk col, 128..191 = Wv col.  Source W is [C][H] row-major.
__global__ __launch_bounds__(256) void wconv_kernel(const float* __restrict__ Wq,
                                                    const float* __restrict__ Wk,
                                                    const float* __restrict__ Wv,
                                                    unsigned short* __restrict__ Wct) {
    int idx = blockIdx.x * 256 + threadIdx.x;   // 0..196607
    int n = idx >> 10;
    int c = idx & 1023;
    int m = n >> 6;
    int h = n & 63;
    const float* W = (m == 0) ? Wq : ((m == 1) ? Wk : Wv);
    float v = W[c * 64 + h];
    if (m == 0) v *= 0.18033688011112042f;  // (1/sqrt(64)) * log2(e)
    Wct[idx] = f2bf(v);
}

// Fused QKV projection: X[16384][1024] fp32 staged once through LDS as bf16
// (XOR-swizzled), 8 waves/block (2 row-groups x 4 col-groups), 32 rows/block.
__global__ __launch_bounds__(512) void proj_kernel(const float* __restrict__ X,
                                                   const unsigned short* __restrict__ Wct,
                                                   unsigned short* __restrict__ Qs,
                                                   unsigned short* __restrict__ Ks,
                                                   unsigned short* __restrict__ Vt) {
    __shared__ short Xs[32 * 1024];   // 64 KB, bf16, swizzled
    char* XsB = (char*)Xs;

    const int tid = threadIdx.x;
    const int rowbase = blockIdx.x * 32;

    #pragma unroll
    for (int i = 0; i < 8; ++i) {
        const int off = i * 4096 + tid * 8;
        const int row = off >> 10;
        const int col = off & 1023;
        const float* xp = X + (size_t)(rowbase + row) * CN + col;
        float4 x0 = *(const float4*)xp;
        float4 x1 = *(const float4*)(xp + 4);
        bf16x8 t;
        t[0] = (short)f2bf(x0.x); t[1] = (short)f2bf(x0.y);
        t[2] = (short)f2bf(x0.z); t[3] = (short)f2bf(x0.w);
        t[4] = (short)f2bf(x1.x); t[5] = (short)f2bf(x1.y);
        t[6] = (short)f2bf(x1.z); t[7] = (short)f2bf(x1.w);
        int addr = (row * 2048 + col * 2) ^ ((row & 7) << 4);
        *(bf16x8*)(XsB + addr) = t;
    }
    __syncthreads();

    const int w  = tid >> 6;        // 0..7
    const int l  = tid & 63;
    const int lq = l & 15;
    const int lg = l >> 4;
    const int wr = w >> 2;          // row-group (16 rows)
    const int wc = w & 3;           // col-group (48 cols)

    const f32x4 zero4 = {0.f, 0.f, 0.f, 0.f};
    f32x4 acc[3] = {zero4, zero4, zero4};

    const unsigned short* wbase0 = Wct + (size_t)(wc * 48 + 0 * 16 + lq) * CN;
    const unsigned short* wbase1 = Wct + (size_t)(wc * 48 + 1 * 16 + lq) * CN;
    const unsigned short* wbase2 = Wct + (size_t)(wc * 48 + 2 * 16 + lq) * CN;

    const int arow = wr * 16 + lq;
    const int abase = arow * 2048;
    const int aswz = (arow & 7) << 4;

    #pragma unroll 4
    for (int kk = 0; kk < 32; ++kk) {
        const int k0 = kk * 32 + lg * 8;
        bf16x8 a = *(const bf16x8*)(XsB + (abase + ((kk * 64 + lg * 16) ^ aswz)));
        bf16x8 b0 = *(const bf16x8*)(wbase0 + k0);
        bf16x8 b1 = *(const bf16x8*)(wbase1 + k0);
        bf16x8 b2 = *(const bf16x8*)(wbase2 + k0);
        acc[0] = __builtin_amdgcn_mfma_f32_16x16x32_bf16(a, b0, acc[0], 0, 0, 0);
        acc[1] = __builtin_amdgcn_mfma_f32_16x16x32_bf16(a, b1, acc[1], 0, 0, 0);
        acc[2] = __builtin_amdgcn_mfma_f32_16x16x32_bf16(a, b2, acc[2], 0, 0, 0);
    }

    #pragma unroll
    for (int j = 0; j < 3; ++j) {
        const int col = wc * 48 + j * 16 + lq;
        const int mtx = col >> 6;          // 0=Q, 1=K, 2=V
        const int h   = col & 63;
        #pragma unroll
        for (int i = 0; i < 4; ++i) {
            const int g = rowbase + wr * 16 + 4 * lg + i;  // global row
            const unsigned short val = f2bf(acc[j][i]);
            if (mtx == 0) {
                Qs[(size_t)g * 64 + h] = val;
            } else if (mtx == 1) {
                Ks[(size_t)g * 64 + h] = val;
            } else {
                const int bb = g >> 11, t = g & 2047;
                Vt[(size_t)((bb << 6) + h) * 2048 + t] = val;
            }
        }
    }
}

// Block-cooperative causal flash attention.
// Block = (batch, q-tile pair {127-pr, pr}) -> exactly 65 key-tiles per block.
// 4 waves split each q-tile's key-tiles round-robin (kt = w, w+4, ...),
// each with private online-softmax state; partials merged in LDS.
// S^T = mfma(K, Q): lane&15 = query, key = 16*fa + 4*(lane>>4) + reg.
__global__ __launch_bounds__(256) void attn_kernel(const unsigned short* __restrict__ Qs,
                                                   const unsigned short* __restrict__ Ks,
                                                   const unsigned short* __restrict__ Vt,
                                                   float* __restrict__ Out) {
    __shared__ float lm[2][4][16];
    __shared__ float ll[2][4][16];
    __shared__ float facc[2][4][1024];

    const int tid = threadIdx.x;
    const int w  = tid >> 6;
    const int l  = tid & 63;
    const int lq = l & 15;
    const int lg = l >> 4;
    const int bid = blockIdx.x;
    const int b  = bid >> 6;
    const int pr = bid & 63;

    const unsigned short* Qb = Qs + (size_t)b * TN * 64;
    const unsigned short* Kb = Ks + (size_t)b * TN * 64;
    const unsigned short* Vb = Vt + (size_t)b * 64 * TN;

    // per-lane invariant offsets
    int koff[4];   // element offsets into K for (fa,ks), tile-local
    #pragma unroll
    for (int fa = 0; fa < 2; ++fa)
        #pragma unroll
        for (int ks = 0; ks < 2; ++ks)
            koff[fa * 2 + ks] = (fa * 16 + lq) * 64 + ks * 32 + lg * 8;
    int voff[4];
    #pragma unroll
    for (int nf = 0; nf < 4; ++nf)
        voff[nf] = (nf * 16 + lq) * 2048 + 4 * lg;

    const f32x4 zero4 = {0.f, 0.f, 0.f, 0.f};

    #pragma unroll
    for (int X = 0; X < 2; ++X) {
        const int qt = (X == 0) ? (127 - pr) : pr;
        const int q0 = qt * 16;
        const int nt = (qt >> 1) + 1;

        bf16x8 qa0 = *(const bf16x8*)(Qb + (size_t)(q0 + lq) * 64 + 0 * 32 + lg * 8);
        bf16x8 qa1 = *(const bf16x8*)(Qb + (size_t)(q0 + lq) * 64 + 1 * 32 + lg * 8);

        f32x4 acc[4] = {zero4, zero4, zero4, zero4};
        float mrow = -1e30f;
        float lrow = 0.f;

        bf16x8 Kc[4], Vc[4], Kn[4], Vn[4];
        int kt = w;
        if (kt < nt) {
            const size_t kb = (size_t)kt * 2048;
            #pragma unroll
            for (int i = 0; i < 4; ++i)
                Kc[i] = *(const bf16x8*)(Kb + kb + koff[i]);
            #pragma unroll
            for (int nf = 0; nf < 4; ++nf) {
                union { bf16x8 v; ushort4 h[2]; } u;
                u.h[0] = *(const ushort4*)(Vb + voff[nf] + kt * 32);
                u.h[1] = *(const ushort4*)(Vb + voff[nf] + kt * 32 + 16);
                Vc[nf] = u.v;
            }
        }

        for (; kt < nt; kt += 4) {
            const int ktn = kt + 4;
            if (ktn < nt) {   // prefetch next tile
                const size_t kb = (size_t)ktn * 2048;
                #pragma unroll
                for (int i = 0; i < 4; ++i)
                    Kn[i] = *(const bf16x8*)(Kb + kb + koff[i]);
                #pragma unroll
                for (int nf = 0; nf < 4; ++nf) {
                    union { bf16x8 v; ushort4 h[2]; } u;
                    u.h[0] = *(const ushort4*)(Vb + voff[nf] + ktn * 32);
                    u.h[1] = *(const ushort4*)(Vb + voff[nf] + ktn * 32 + 16);
                    Vn[nf] = u.v;
                }
            }

            const int key0 = kt * 32;
            f32x4 s[2];
            s[0] = __builtin_amdgcn_mfma_f32_16x16x32_bf16(Kc[0], qa0, zero4, 0, 0, 0);
            s[0] = __builtin_amdgcn_mfma_f32_16x16x32_bf16(Kc[1], qa1, s[0], 0, 0, 0);
            s[1] = __builtin_amdgcn_mfma_f32_16x16x32_bf16(Kc[2], qa0, zero4, 0, 0, 0);
            s[1] = __builtin_amdgcn_mfma_f32_16x16x32_bf16(Kc[3], qa1, s[1], 0, 0, 0);

            if (kt == nt - 1) {   // only the diagonal tile needs masking
                const int q = q0 + lq;
                #pragma unroll
                for (int fa = 0; fa < 2; ++fa)
                    #pragma unroll
                    for (int r = 0; r < 4; ++r) {
                        const int key = key0 + fa * 16 + 4 * lg + r;
                        if (key > q) s[fa][r] = -1e30f;
                    }
            }

            // row max (lane&15 = query domain), max3-shaped tree
            float m1 = fmaxf(fmaxf(s[0][0], s[0][1]), s[0][2]);
            float m2 = fmaxf(fmaxf(s[0][3], s[1][0]), s[1][1]);
            float m3 = fmaxf(fmaxf(s[1][2], s[1][3]), m1);
            float tm = fmaxf(m2, m3);
            tm = fmaxf(tm, __shfl_xor(tm, 16));
            tm = fmaxf(tm, __shfl_xor(tm, 32));

            // defer-max: only rescale when max grows by > 8 (P bounded by 2^8)
            if (!__all(tm <= mrow + 8.0f)) {
                const float mnew = fmaxf(mrow, tm);
                const float cc = __builtin_amdgcn_exp2f(mrow - mnew);
                lrow *= cc;
                float cb[4];
                #pragma unroll
                for (int i = 0; i < 4; ++i) cb[i] = __shfl(cc, 4 * lg + i);
                #pragma unroll
                for (int nf = 0; nf < 4; ++nf)
                    #pragma unroll
                    for (int i = 0; i < 4; ++i) acc[nf][i] *= cb[i];
                mrow = mnew;
            }

            float p[2][4];
            float psum = 0.f;
            #pragma unroll
            for (int fa = 0; fa < 2; ++fa)
                #pragma unroll
                for (int r = 0; r < 4; ++r) {
                    p[fa][r] = __builtin_amdgcn_exp2f(s[fa][r] - mrow);
                    psum += p[fa][r];
                }
            psum += __shfl_xor(psum, 16);
            psum += __shfl_xor(psum, 32);
            lrow += psum;

            bf16x8 pa;
            pa[0] = (short)f2bf(p[0][0]); pa[1] = (short)f2bf(p[0][1]);
            pa[2] = (short)f2bf(p[0][2]); pa[3] = (short)f2bf(p[0][3]);
            pa[4] = (short)f2bf(p[1][0]); pa[5] = (short)f2bf(p[1][1]);
            pa[6] = (short)f2bf(p[1][2]); pa[7] = (short)f2bf(p[1][3]);

            acc[0] = __builtin_amdgcn_mfma_f32_16x16x32_bf16(pa, Vc[0], acc[0], 0, 0, 0);
            acc[1] = __builtin_amdgcn_mfma_f32_16x16x32_bf16(pa, Vc[1], acc[1], 0, 0, 0);
            acc[2] = __builtin_amdgcn_mfma_f32_16x16x32_bf16(pa, Vc[2], acc[2], 0, 0, 0);
            acc[3] = __builtin_amdgcn_mfma_f32_16x16x32_bf16(pa, Vc[3], acc[3], 0, 0, 0);

            #pragma unroll
            for (int i = 0; i < 4; ++i) { Kc[i] = Kn[i]; Vc[i] = Vn[i]; }
        }

        // store partial state to LDS
        if (lg == 0) {
            lm[X][w][lq] = mrow;
            ll[X][w][lq] = lrow;
        }
        #pragma unroll
        for (int nf = 0; nf < 4; ++nf)
            #pragma unroll
            for (int i = 0; i < 4; ++i)
                facc[X][w][(4 * lg + i) * 64 + nf * 16 + lq] = acc[nf][i];
    }

    __syncthreads();

    // merge 4 wave-partials per q-tile and write Out
    #pragma unroll
    for (int X = 0; X < 2; ++X) {
        const int qt = (X == 0) ? (127 - pr) : pr;
        const int q0 = qt * 16;
        #pragma unroll
        for (int ii = 0; ii < 4; ++ii) {
            const int e = tid + ii * 256;
            const int q = e >> 6;
            const int h = e & 63;
            const float M = fmaxf(fmaxf(lm[X][0][q], lm[X][1][q]),
                                  fmaxf(lm[X][2][q], lm[X][3][q]));
            float L = 0.f, O = 0.f;
            #pragma unroll
            for (int c = 0; c < 4; ++c) {
                const float wgt = __builtin_amdgcn_exp2f(lm[X][c][q] - M);
                L += wgt * ll[X][c][q];
                O += wgt * facc[X][c][q * 64 + h];
            }
            Out[((size_t)b * TN + q0 + q) * 64 + h] = O / L;
        }
    }
}

extern "C" void kernel_launch(void* const* d_in, const int* in_sizes, int n_in,
                              void* d_out, int out_size, void* d_ws, size_t ws_size,
                              hipStream_t stream) {
    const float* X  = (const float*)d_in[0];
    const float* Wq = (const float*)d_in[1];
    const float* Wk = (const float*)d_in[2];
    const float* Wv = (const float*)d_in[3];
    float* Out = (float*)d_out;

    char* ws = (char*)d_ws;
    unsigned short* Wct = (unsigned short*)(ws);                 // 384 KB (pad 512 KB)
    unsigned short* Qs  = (unsigned short*)(ws + (512u << 10));  // 2 MB
    unsigned short* Ks  = Qs + (size_t)16384 * 64;               // 2 MB
    unsigned short* Vt  = Ks + (size_t)16384 * 64;               // 2 MB

    hipLaunchKernelGGL(wconv_kernel, dim3(768), dim3(256), 0, stream, Wq, Wk, Wv, Wct);
    hipLaunchKernelGGL(proj_kernel,  dim3(512), dim3(512), 0, stream, X, Wct, Qs, Ks, Vt);
    hipLaunchKernelGGL(attn_kernel,  dim3(512), dim3(256), 0, stream, Qs, Ks, Vt, Out);
}